// Round 1
// baseline (293.628 us; speedup 1.0000x reference)
//
#include <hip/hip_runtime.h>

#define HID 1024
#define SEQ 2048
#define NB 2
#define NH 16
#define HD 64
#define GAMMA 0.5f

typedef __attribute__((ext_vector_type(8))) short bf16x8;
typedef __attribute__((ext_vector_type(8))) unsigned short u16x8;
typedef __attribute__((ext_vector_type(4))) float f32x4;

__device__ __forceinline__ unsigned short f2bf(float f) {
  unsigned u = __builtin_bit_cast(unsigned, f);
  u += 0x7fffu + ((u >> 16) & 1u);
  return (unsigned short)(u >> 16);
}

// ---- convert the 4 weight matrices f32 -> bf16 into one contiguous buffer ----
__global__ __launch_bounds__(256) void convert_w_kernel(
    const float* __restrict__ Wq, const float* __restrict__ Wk,
    const float* __restrict__ Wv, const float* __restrict__ Wo,
    unsigned short* __restrict__ Wb) {
  int i = blockIdx.x * 256 + threadIdx.x;  // 524288 threads, 8 elems each
  const int per = (HID * HID) / 8;         // 131072
  int m = i / per;
  const float* sp = (m == 0) ? Wq : (m == 1) ? Wk : (m == 2) ? Wv : Wo;
  int j = (i - m * per) * 8;
  const float4* p = reinterpret_cast<const float4*>(sp + j);
  float4 a = p[0], b = p[1];
  u16x8 o;
  o[0] = f2bf(a.x); o[1] = f2bf(a.y); o[2] = f2bf(a.z); o[3] = f2bf(a.w);
  o[4] = f2bf(b.x); o[5] = f2bf(b.y); o[6] = f2bf(b.z); o[7] = f2bf(b.w);
  *reinterpret_cast<u16x8*>(Wb + (size_t)i * 8) = o;
}

// ---- per-row L2 norm of x; emit x (bf16) and normalized x (bf16) ----
__global__ __launch_bounds__(256) void rownorm_kernel(
    const float* __restrict__ x, unsigned short* __restrict__ xb,
    unsigned short* __restrict__ nxb) {
  int row = blockIdx.x, tid = threadIdx.x;
  const float4 v = reinterpret_cast<const float4*>(x + (size_t)row * HID)[tid];
  float ss = v.x * v.x + v.y * v.y + v.z * v.z + v.w * v.w;
#pragma unroll
  for (int off = 32; off; off >>= 1) ss += __shfl_xor(ss, off, 64);
  __shared__ float wsum[4];
  if ((tid & 63) == 0) wsum[tid >> 6] = ss;
  __syncthreads();
  float tot = wsum[0] + wsum[1] + wsum[2] + wsum[3];
  float inv = 1.0f / fmaxf(sqrtf(tot), 1e-12f);
  ushort4 a, b;
  a.x = f2bf(v.x); a.y = f2bf(v.y); a.z = f2bf(v.z); a.w = f2bf(v.w);
  b.x = f2bf(v.x * inv); b.y = f2bf(v.y * inv);
  b.z = f2bf(v.z * inv); b.w = f2bf(v.w * inv);
  reinterpret_cast<ushort4*>(xb  + (size_t)row * HID)[tid] = a;
  reinterpret_cast<ushort4*>(nxb + (size_t)row * HID)[tid] = b;
}

// ---- generic NT bf16 GEMM: C = A[M,K] * B[N,K]^T, f32 accum ----
// MODE 0: bf16 out, bias via 3-way pointer select (QKV fused / generic)
// MODE 1: f32 out = GAMMA*acc + (mask ? 1e30 : 0)   (diversity bias matrix)
// MODE 2: f32 out + bias                             (final projection)
template <int MODE>
__global__ __launch_bounds__(256) void gemm_nt(
    const unsigned short* __restrict__ A, long strideA,
    const unsigned short* __restrict__ B, long strideB,
    void* __restrict__ Cv, long strideC, int ldc,
    int M, int N, int K,
    const float* __restrict__ b0, const float* __restrict__ b1,
    const float* __restrict__ b2, const unsigned char* __restrict__ mask) {
  __shared__ __align__(16) unsigned short As[128][40];
  __shared__ __align__(16) unsigned short Bs[128][40];
  int tid = threadIdx.x, lane = tid & 63, wid = tid >> 6;
  int g = lane >> 4, lr = lane & 15;
  int wr = wid >> 1, wc = wid & 1;
  int m0 = blockIdx.y * 128, n0 = blockIdx.x * 128;
  const unsigned short* Ab = A + (size_t)blockIdx.z * strideA;
  const unsigned short* Bb = B + (size_t)blockIdx.z * strideB;
  f32x4 acc[4][4] = {};
  for (int k0 = 0; k0 < K; k0 += 32) {
#pragma unroll
    for (int p = 0; p < 2; p++) {
      int u = tid + p * 256;
      int row = u >> 2, ch = u & 3;
      *reinterpret_cast<u16x8*>(&As[row][ch * 8]) =
          *reinterpret_cast<const u16x8*>(Ab + (size_t)(m0 + row) * K + k0 + ch * 8);
      *reinterpret_cast<u16x8*>(&Bs[row][ch * 8]) =
          *reinterpret_cast<const u16x8*>(Bb + (size_t)(n0 + row) * K + k0 + ch * 8);
    }
    __syncthreads();
    bf16x8 af[4], bfr[4];
#pragma unroll
    for (int i = 0; i < 4; i++) {
      af[i]  = *reinterpret_cast<const bf16x8*>(&As[wr * 64 + i * 16 + lr][g * 8]);
      bfr[i] = *reinterpret_cast<const bf16x8*>(&Bs[wc * 64 + i * 16 + lr][g * 8]);
    }
#pragma unroll
    for (int i = 0; i < 4; i++)
#pragma unroll
      for (int j = 0; j < 4; j++)
        acc[i][j] = __builtin_amdgcn_mfma_f32_16x16x32_bf16(af[i], bfr[j], acc[i][j], 0, 0, 0);
    __syncthreads();
  }
#pragma unroll
  for (int i = 0; i < 4; i++)
#pragma unroll
    for (int j = 0; j < 4; j++) {
      int col = n0 + wc * 64 + j * 16 + lr;
#pragma unroll
      for (int r = 0; r < 4; r++) {
        int row = m0 + wr * 64 + i * 16 + 4 * g + r;
        float v = acc[i][j][r];
        if (MODE == 0) {
          const float* bp = (col < 1024) ? b0 : (col < 2048 ? b1 : b2);
          v += bp[col & 1023];
          ((unsigned short*)Cv)[(size_t)blockIdx.z * strideC + (size_t)row * ldc + col] = f2bf(v);
        } else if (MODE == 1) {
          v = GAMMA * v + (mask[(size_t)row * N + col] ? 1e30f : 0.0f);
          ((float*)Cv)[(size_t)blockIdx.z * strideC + (size_t)row * ldc + col] = v;
        } else {
          v += b0[col];
          ((float*)Cv)[(size_t)blockIdx.z * strideC + (size_t)row * ldc + col] = v;
        }
      }
    }
}

// ---- flash attention with additive diversity bias ----
// grid (qt=32, h=16, b=2), 256 thr = 4 waves; wave owns 16 q-rows, KT=64.
__global__ __launch_bounds__(256) void flash_kernel(
    const unsigned short* __restrict__ QKV,  // [4096][3072] bf16 (Q|K|V)
    const float* __restrict__ Dbias,         // [2][2048][2048]
    unsigned short* __restrict__ ctxb) {     // [4096][1024] bf16
  int qt = blockIdx.x, h = blockIdx.y, b = blockIdx.z;
  int tid = threadIdx.x, wid = tid >> 6, lane = tid & 63;
  int g = lane >> 4, lr = lane & 15;
  __shared__ __align__(16) unsigned short Ks[64][72];
  __shared__ __align__(16) unsigned short Vt[64][72];
  __shared__ __align__(16) unsigned short Pl[4][16][72];
  const size_t ld = 3 * HID;
  size_t rowQ = (size_t)b * SEQ + qt * 64 + wid * 16 + lr;
  bf16x8 qf[2];
  qf[0] = *reinterpret_cast<const bf16x8*>(QKV + rowQ * ld + h * HD + g * 8);
  qf[1] = *reinterpret_cast<const bf16x8*>(QKV + rowQ * ld + h * HD + 32 + g * 8);
  f32x4 acc[4] = {};
  float mrow[4], lrow[4];
#pragma unroll
  for (int r = 0; r < 4; r++) { mrow[r] = -3e38f; lrow[r] = 0.0f; }
  const float* Db = Dbias + (size_t)b * SEQ * SEQ;
  const int qloc = qt * 64 + wid * 16 + 4 * g;

  for (int kt = 0; kt < SEQ / 64; kt++) {
    // stage K tile [64 keys][64 d]
#pragma unroll
    for (int p = 0; p < 2; p++) {
      int u = tid + p * 256;
      int krow = u >> 3, ch = u & 7;
      *reinterpret_cast<u16x8*>(&Ks[krow][ch * 8]) = *reinterpret_cast<const u16x8*>(
          QKV + ((size_t)b * SEQ + kt * 64 + krow) * ld + HID + h * HD + ch * 8);
    }
    // stage V tile transposed: Vt[d][key]
#pragma unroll
    for (int p = 0; p < 2; p++) {
      int u = tid + p * 256;
      int krow = u >> 3, ch = u & 7;
      u16x8 vv = *reinterpret_cast<const u16x8*>(
          QKV + ((size_t)b * SEQ + kt * 64 + krow) * ld + 2 * HID + h * HD + ch * 8);
#pragma unroll
      for (int i = 0; i < 8; i++) Vt[ch * 8 + i][krow] = vv[i];
    }
    __syncthreads();

    // S = Q K^T for this wave's 16 q-rows x 64 keys
    f32x4 s[4];
#pragma unroll
    for (int kc = 0; kc < 4; kc++) {
      bf16x8 k0 = *reinterpret_cast<const bf16x8*>(&Ks[kc * 16 + lr][g * 8]);
      bf16x8 k1 = *reinterpret_cast<const bf16x8*>(&Ks[kc * 16 + lr][32 + g * 8]);
      f32x4 z = {};
      z = __builtin_amdgcn_mfma_f32_16x16x32_bf16(qf[0], k0, z, 0, 0, 0);
      s[kc] = __builtin_amdgcn_mfma_f32_16x16x32_bf16(qf[1], k1, z, 0, 0, 0);
    }
    // scale + diversity bias
#pragma unroll
    for (int kc = 0; kc < 4; kc++) {
      int key = kt * 64 + kc * 16 + lr;
#pragma unroll
      for (int r = 0; r < 4; r++) {
        float d = Db[(size_t)(qloc + r) * SEQ + key];
        s[kc][r] = s[kc][r] * 0.125f - d;
      }
    }
    // online softmax (per q-row r, reduce across 16 lanes of group g)
    float pm[4], scale[4], rs[4];
#pragma unroll
    for (int r = 0; r < 4; r++) {
      pm[r] = fmaxf(fmaxf(s[0][r], s[1][r]), fmaxf(s[2][r], s[3][r]));
#pragma unroll
      for (int off = 1; off < 16; off <<= 1) pm[r] = fmaxf(pm[r], __shfl_xor(pm[r], off, 64));
      float mn = fmaxf(mrow[r], pm[r]);
      scale[r] = __expf(mrow[r] - mn);
      mrow[r] = mn;
      rs[r] = 0.0f;
    }
#pragma unroll
    for (int kc = 0; kc < 4; kc++)
#pragma unroll
      for (int r = 0; r < 4; r++) {
        s[kc][r] = __expf(s[kc][r] - mrow[r]);
        rs[r] += s[kc][r];
      }
#pragma unroll
    for (int r = 0; r < 4; r++) {
#pragma unroll
      for (int off = 1; off < 16; off <<= 1) rs[r] += __shfl_xor(rs[r], off, 64);
      lrow[r] = lrow[r] * scale[r] + rs[r];
    }
#pragma unroll
    for (int df = 0; df < 4; df++)
#pragma unroll
      for (int r = 0; r < 4; r++) acc[df][r] *= scale[r];
    // P -> LDS (bf16)
#pragma unroll
    for (int kc = 0; kc < 4; kc++)
#pragma unroll
      for (int r = 0; r < 4; r++) Pl[wid][4 * g + r][kc * 16 + lr] = f2bf(s[kc][r]);
    __syncthreads();  // cross-lane P visibility (and keeps waves in step)
    // ctx += P V
#pragma unroll
    for (int c2 = 0; c2 < 2; c2++) {
      bf16x8 pf = *reinterpret_cast<const bf16x8*>(&Pl[wid][lr][c2 * 32 + g * 8]);
#pragma unroll
      for (int df = 0; df < 4; df++) {
        bf16x8 vf = *reinterpret_cast<const bf16x8*>(&Vt[df * 16 + lr][c2 * 32 + g * 8]);
        acc[df] = __builtin_amdgcn_mfma_f32_16x16x32_bf16(pf, vf, acc[df], 0, 0, 0);
      }
    }
    __syncthreads();  // protect Ks/Vt before next stage
  }
  size_t orow = (size_t)b * SEQ + qt * 64 + wid * 16 + 4 * g;
#pragma unroll
  for (int r = 0; r < 4; r++) {
    float invl = 1.0f / lrow[r];
#pragma unroll
    for (int df = 0; df < 4; df++)
      ctxb[(orow + r) * HID + h * HD + df * 16 + lr] = f2bf(acc[df][r] * invl);
  }
}

extern "C" void kernel_launch(void* const* d_in, const int* in_sizes, int n_in,
                              void* d_out, int out_size, void* d_ws, size_t ws_size,
                              hipStream_t stream) {
  const float* x = (const float*)d_in[0];
  const unsigned char* mask = (const unsigned char*)d_in[1];
  const float* Wq = (const float*)d_in[2];
  const float* bq = (const float*)d_in[3];
  const float* Wk = (const float*)d_in[4];
  const float* bk = (const float*)d_in[5];
  const float* Wv = (const float*)d_in[6];
  const float* bv = (const float*)d_in[7];
  const float* Wo = (const float*)d_in[8];
  const float* bo = (const float*)d_in[9];
  float* out = (float*)d_out;

  char* ws = (char*)d_ws;
  const size_t MiB = 1024 * 1024;
  unsigned short* xb  = (unsigned short*)(ws + 0 * MiB);   // 8 MiB
  unsigned short* nxb = (unsigned short*)(ws + 8 * MiB);   // 8 MiB
  unsigned short* Wb  = (unsigned short*)(ws + 16 * MiB);  // 8 MiB (Wq|Wk|Wv|Wo bf16)
  unsigned short* QKV = (unsigned short*)(ws + 24 * MiB);  // 24 MiB [4096][3072]
  float* simD         = (float*)(ws + 48 * MiB);           // 32 MiB [2][2048][2048]
  unsigned short* ctx = (unsigned short*)(ws + 80 * MiB);  // 8 MiB

  convert_w_kernel<<<2048, 256, 0, stream>>>(Wq, Wk, Wv, Wo, Wb);
  rownorm_kernel<<<NB * SEQ, 256, 0, stream>>>(x, xb, nxb);
  // fused QKV projection: [4096,1024] x [3072,1024]^T -> [4096,3072] bf16
  gemm_nt<0><<<dim3(24, 32, 1), 256, 0, stream>>>(
      xb, 0, Wb, 0, QKV, 0, 3 * HID, NB * SEQ, 3 * HID, HID, bq, bk, bv, nullptr);
  // diversity bias matrix per batch: D = GAMMA * nx nx^T (+1e30 where masked)
  gemm_nt<1><<<dim3(16, 16, 2), 256, 0, stream>>>(
      nxb, (long)SEQ * HID, nxb, (long)SEQ * HID, simD, (long)SEQ * SEQ, SEQ,
      SEQ, SEQ, HID, nullptr, nullptr, nullptr, mask);
  // flash attention over all heads
  flash_kernel<<<dim3(SEQ / 64, NH, NB), 256, 0, stream>>>(QKV, simD, ctx);
  // output projection: [4096,1024] x [1024,1024]^T + bo -> f32 out
  gemm_nt<2><<<dim3(8, 32, 1), 256, 0, stream>>>(
      ctx, 0, Wb + (size_t)3 * HID * HID, 0, out, 0, HID, NB * SEQ, HID, HID,
      bo, nullptr, nullptr, nullptr);
}

// Round 3
// 231.394 us; speedup vs baseline: 1.2690x; 1.2690x over previous
//
#include <hip/hip_runtime.h>

#define HID 1024
#define SEQ 2048
#define NB 2
#define NH 16
#define HD 64

// 0.125 * log2(e)  (1/sqrt(64) fold into log2 domain)
#define C1 0.1803368801111204f
// gamma * log2(e)
#define C2 0.7213475204444817f

typedef __attribute__((ext_vector_type(8))) short bf16x8;
typedef __attribute__((ext_vector_type(8))) unsigned short u16x8;
typedef __attribute__((ext_vector_type(4))) float f32x4;

__device__ __forceinline__ unsigned short f2bf(float f) {
  unsigned u = __builtin_bit_cast(unsigned, f);
  u += 0x7fffu + ((u >> 16) & 1u);
  return (unsigned short)(u >> 16);
}
__device__ __forceinline__ float bf2f(unsigned short u) {
  return __builtin_bit_cast(float, ((unsigned)u) << 16);
}

#define GLOAD16(gsrc, ldst)                                                     \
  __builtin_amdgcn_global_load_lds(                                             \
      (const __attribute__((address_space(1))) void*)(gsrc),                    \
      (__attribute__((address_space(3))) void*)(ldst), 16, 0, 0)

// ---- convert the 4 weight matrices f32 -> bf16 into one contiguous buffer ----
__global__ __launch_bounds__(256) void convert_w_kernel(
    const float* __restrict__ Wq, const float* __restrict__ Wk,
    const float* __restrict__ Wv, const float* __restrict__ Wo,
    unsigned short* __restrict__ Wb) {
  int i = blockIdx.x * 256 + threadIdx.x;
  const int per = (HID * HID) / 8;
  int m = i / per;
  const float* sp = (m == 0) ? Wq : (m == 1) ? Wk : (m == 2) ? Wv : Wo;
  int j = (i - m * per) * 8;
  const float4* p = reinterpret_cast<const float4*>(sp + j);
  float4 a = p[0], b = p[1];
  u16x8 o;
  o[0] = f2bf(a.x); o[1] = f2bf(a.y); o[2] = f2bf(a.z); o[3] = f2bf(a.w);
  o[4] = f2bf(b.x); o[5] = f2bf(b.y); o[6] = f2bf(b.z); o[7] = f2bf(b.w);
  *reinterpret_cast<u16x8*>(Wb + (size_t)i * 8) = o;
}

// ---- per-row L2 norm of x; emit x (bf16) and normalized x (bf16) ----
__global__ __launch_bounds__(256) void rownorm_kernel(
    const float* __restrict__ x, unsigned short* __restrict__ xb,
    unsigned short* __restrict__ nxb) {
  int row = blockIdx.x, tid = threadIdx.x;
  const float4 v = reinterpret_cast<const float4*>(x + (size_t)row * HID)[tid];
  float ss = v.x * v.x + v.y * v.y + v.z * v.z + v.w * v.w;
#pragma unroll
  for (int off = 32; off; off >>= 1) ss += __shfl_xor(ss, off, 64);
  __shared__ float wsum[4];
  if ((tid & 63) == 0) wsum[tid >> 6] = ss;
  __syncthreads();
  float tot = wsum[0] + wsum[1] + wsum[2] + wsum[3];
  float inv = 1.0f / fmaxf(sqrtf(tot), 1e-12f);
  ushort4 a, b;
  a.x = f2bf(v.x); a.y = f2bf(v.y); a.z = f2bf(v.z); a.w = f2bf(v.w);
  b.x = f2bf(v.x * inv); b.y = f2bf(v.y * inv);
  b.z = f2bf(v.z * inv); b.w = f2bf(v.w * inv);
  reinterpret_cast<ushort4*>(xb  + (size_t)row * HID)[tid] = a;
  reinterpret_cast<ushort4*>(nxb + (size_t)row * HID)[tid] = b;
}

// ---- generic NT bf16 GEMM: C = A[M,K] * B[N,K]^T, f32 accum ----
// MODE 0: bf16 out, bias via 3-way pointer select (QKV fused)
// MODE 1: bf16 out = -C2*acc + (mask ? -1e30 : 0)   (log2-domain diversity bias)
// MODE 2: f32 out + bias                             (final projection)
template <int MODE>
__global__ __launch_bounds__(256) void gemm_nt(
    const unsigned short* __restrict__ A, long strideA,
    const unsigned short* __restrict__ B, long strideB,
    void* __restrict__ Cv, long strideC, int ldc,
    int M, int N, int K,
    const float* __restrict__ b0, const float* __restrict__ b1,
    const float* __restrict__ b2, const unsigned char* __restrict__ mask) {
  __shared__ __align__(16) unsigned short As[128][40];
  __shared__ __align__(16) unsigned short Bs[128][40];
  int tid = threadIdx.x, lane = tid & 63, wid = tid >> 6;
  int g = lane >> 4, lr = lane & 15;
  int wr = wid >> 1, wc = wid & 1;
  int m0 = blockIdx.y * 128, n0 = blockIdx.x * 128;
  const unsigned short* Ab = A + (size_t)blockIdx.z * strideA;
  const unsigned short* Bb = B + (size_t)blockIdx.z * strideB;
  f32x4 acc[4][4] = {};
  for (int k0 = 0; k0 < K; k0 += 32) {
#pragma unroll
    for (int p = 0; p < 2; p++) {
      int u = tid + p * 256;
      int row = u >> 2, chk = u & 3;
      *reinterpret_cast<u16x8*>(&As[row][chk * 8]) =
          *reinterpret_cast<const u16x8*>(Ab + (size_t)(m0 + row) * K + k0 + chk * 8);
      *reinterpret_cast<u16x8*>(&Bs[row][chk * 8]) =
          *reinterpret_cast<const u16x8*>(Bb + (size_t)(n0 + row) * K + k0 + chk * 8);
    }
    __syncthreads();
    bf16x8 af[4], bfr[4];
#pragma unroll
    for (int i = 0; i < 4; i++) {
      af[i]  = *reinterpret_cast<const bf16x8*>(&As[wr * 64 + i * 16 + lr][g * 8]);
      bfr[i] = *reinterpret_cast<const bf16x8*>(&Bs[wc * 64 + i * 16 + lr][g * 8]);
    }
#pragma unroll
    for (int i = 0; i < 4; i++)
#pragma unroll
      for (int j = 0; j < 4; j++)
        acc[i][j] = __builtin_amdgcn_mfma_f32_16x16x32_bf16(af[i], bfr[j], acc[i][j], 0, 0, 0);
    __syncthreads();
  }
#pragma unroll
  for (int i = 0; i < 4; i++)
#pragma unroll
    for (int j = 0; j < 4; j++) {
      int col = n0 + wc * 64 + j * 16 + lr;
#pragma unroll
      for (int r = 0; r < 4; r++) {
        int row = m0 + wr * 64 + i * 16 + 4 * g + r;
        float v = acc[i][j][r];
        if (MODE == 0) {
          const float* bp = (col < 1024) ? b0 : (col < 2048 ? b1 : b2);
          v += bp[col & 1023];
          ((unsigned short*)Cv)[(size_t)blockIdx.z * strideC + (size_t)row * ldc + col] = f2bf(v);
        } else if (MODE == 1) {
          float t = -C2 * v + (mask[(size_t)row * N + col] ? -1e30f : 0.0f);
          ((unsigned short*)Cv)[(size_t)blockIdx.z * strideC + (size_t)row * ldc + col] = f2bf(t);
        } else {
          v += b0[col];
          ((float*)Cv)[(size_t)blockIdx.z * strideC + (size_t)row * ldc + col] = v;
        }
      }
    }
}

// ---- flash attention with additive diversity bias (swapped-QK^T layout) ----
// grid (qt=16, h=16, b=2), 512 thr = 8 waves; wave owns 16 q-rows, KVBLK=64.
// S^T = mfma(K,Q): lane (g,lr) holds S[key=kc*16+4g+r][q=lr] -> per-lane softmax.
__global__ __launch_bounds__(512) void flash_kernel(
    const unsigned short* __restrict__ QKV,  // [4096][3072] bf16 (Q|K|V)
    const unsigned short* __restrict__ D2,   // [2][2048][2048] bf16 log2-bias
    unsigned short* __restrict__ ctxb) {     // [4096][1024] bf16
  int qt = blockIdx.x, h = blockIdx.y, b = blockIdx.z;
  int tid = threadIdx.x, wid = tid >> 6, lane = tid & 63;
  int g = lane >> 4, lr = lane & 15;
  __shared__ __align__(16) unsigned short Ks[2][64 * 64];
  __shared__ __align__(16) unsigned short Vt[2][64 * 64];
  __shared__ __align__(16) unsigned short Pl[8][16 * 72];
  const size_t ld = 3 * HID;
  const size_t bS = (size_t)b * SEQ;

  // Q fragment (B operand): rows wid*16+lr, lane group g holds d = 8g+j (+32)
  const unsigned short* qp = QKV + (bS + qt * 128 + wid * 16 + lr) * ld + h * HD;
  bf16x8 qf0 = *reinterpret_cast<const bf16x8*>(qp + g * 8);
  bf16x8 qf1 = *reinterpret_cast<const bf16x8*>(qp + 32 + g * 8);

  // K staging: global_load_lds, source pre-swizzled so LDS slot (row, c') holds
  // K[row][chunk c' ^ (row&7)]  (row&7 == lane>>3, thread-invariant)
  const unsigned short* gK = QKV + (bS + wid * 8 + (lane >> 3)) * ld + HID + h * HD
                             + (((lane & 7) ^ (lane >> 3)) << 3);
  // V staging: reg -> swizzled scalar transpose writes (conflict-free)
  const unsigned short* gV = QKV + (bS + (tid >> 3)) * ld + 2 * HID + h * HD + ((tid & 7) << 3);
  const int ch = tid & 7, kr3 = (tid >> 3) & 7, kb = tid >> 6;
  const int vtbase = ch * 512 + kr3;
  const int pre7 = (kb ^ ch) & 7;

  // log2-domain bias row pointer (lane owns q = qt*128+wid*16+lr)
  const unsigned short* bD = D2 + (size_t)b * SEQ * SEQ
                             + (size_t)(qt * 128 + wid * 16 + lr) * SEQ + 4 * g;

  // prologue: stage tile 0 into buffer 0
  GLOAD16(gK, &Ks[0][0] + wid * 512);
  {
    u16x8 vv = *reinterpret_cast<const u16x8*>(gV);
#pragma unroll
    for (int i = 0; i < 8; i++)
      Vt[0][vtbase + i * 64 + ((pre7 ^ i) << 3)] = vv[i];
  }
  __syncthreads();

  f32x4 acc[4] = {};
  float mrun = -1e30f, lrun = 0.0f;
  const int kb0 = lr * 64 + ((g ^ (lr & 7)) << 3);

  for (int kt = 0; kt < 32; ++kt) {
    const int cb = kt & 1;
    const unsigned short* ks = &Ks[cb][0];
    const unsigned short* vt = &Vt[cb][0];
    u16x8 vv2 = {};
    if (kt < 31) {  // prefetch next tile into other buffer
      GLOAD16(gK + (size_t)(kt + 1) * 64 * ld, &Ks[cb ^ 1][0] + wid * 512);
      vv2 = *reinterpret_cast<const u16x8*>(gV + (size_t)(kt + 1) * 64 * ld);
    }
    // bias loads (vectorized, contiguous along key)
    ushort4 bv4[4];
#pragma unroll
    for (int kc = 0; kc < 4; kc++)
      bv4[kc] = *reinterpret_cast<const ushort4*>(bD + kt * 64 + kc * 16);

    // S^T = K Q^T  (A = K frag, B = Q frag)
    f32x4 s[4];
#pragma unroll
    for (int kc = 0; kc < 4; kc++) {
      bf16x8 kf0 = *reinterpret_cast<const bf16x8*>(ks + kc * 1024 + kb0);
      bf16x8 kf1 = *reinterpret_cast<const bf16x8*>(ks + kc * 1024 + (kb0 ^ 32));
      f32x4 z = {};
      z = __builtin_amdgcn_mfma_f32_16x16x32_bf16(kf0, qf0, z, 0, 0, 0);
      s[kc] = __builtin_amdgcn_mfma_f32_16x16x32_bf16(kf1, qf1, z, 0, 0, 0);
    }
    // scale + bias (log2 domain), per-lane max
    float mx = mrun;
#pragma unroll
    for (int kc = 0; kc < 4; kc++) {
      s[kc][0] = fmaf(s[kc][0], C1, bf2f(bv4[kc].x));
      s[kc][1] = fmaf(s[kc][1], C1, bf2f(bv4[kc].y));
      s[kc][2] = fmaf(s[kc][2], C1, bf2f(bv4[kc].z));
      s[kc][3] = fmaf(s[kc][3], C1, bf2f(bv4[kc].w));
      mx = fmaxf(mx, fmaxf(fmaxf(s[kc][0], s[kc][1]), fmaxf(s[kc][2], s[kc][3])));
    }
    mx = fmaxf(mx, __shfl_xor(mx, 16, 64));
    mx = fmaxf(mx, __shfl_xor(mx, 32, 64));
    float sc = exp2f(mrun - mx);
    mrun = mx;
    // P = exp2(s - mx), row-sum, store P (bf16) to per-wave LDS
    float rs = 0.0f;
#pragma unroll
    for (int kc = 0; kc < 4; kc++) {
      float p0 = exp2f(s[kc][0] - mx), p1 = exp2f(s[kc][1] - mx);
      float p2 = exp2f(s[kc][2] - mx), p3 = exp2f(s[kc][3] - mx);
      rs += (p0 + p1) + (p2 + p3);
      ushort4 pk;
      pk.x = f2bf(p0); pk.y = f2bf(p1); pk.z = f2bf(p2); pk.w = f2bf(p3);
      *reinterpret_cast<ushort4*>(&Pl[wid][lr * 72 + kc * 16 + 4 * g]) = pk;
    }
    rs += __shfl_xor(rs, 16, 64);
    rs += __shfl_xor(rs, 32, 64);
    lrun = lrun * sc + rs;
    // rescale accumulator (acc rows are q = 4g+r; stats live at lane lr=q)
    float s0 = __shfl(sc, 4 * g + 0, 16), s1 = __shfl(sc, 4 * g + 1, 16);
    float s2 = __shfl(sc, 4 * g + 2, 16), s3 = __shfl(sc, 4 * g + 3, 16);
#pragma unroll
    for (int df = 0; df < 4; df++) {
      acc[df][0] *= s0; acc[df][1] *= s1; acc[df][2] *= s2; acc[df][3] *= s3;
    }
    // write next V tile (waits on vv2 loads; overlapped with the above)
    if (kt < 31) {
#pragma unroll
      for (int i = 0; i < 8; i++)
        Vt[cb ^ 1][vtbase + i * 64 + ((pre7 ^ i) << 3)] = vv2[i];
    }
    // ctx += P V   (A = P frag, B = V^T frag from swizzled Vt)
#pragma unroll
    for (int c2 = 0; c2 < 2; c2++) {
      bf16x8 pf = *reinterpret_cast<const bf16x8*>(&Pl[wid][lr * 72 + c2 * 32 + g * 8]);
#pragma unroll
      for (int df = 0; df < 4; df++) {
        int blk = ((4 * c2 + g) ^ (lr & 7) ^ ((df * 2 + (lr >> 3)) & 7)) & 7;
        bf16x8 vf = *reinterpret_cast<const bf16x8*>(vt + (df * 16 + lr) * 64 + (blk << 3));
        acc[df] = __builtin_amdgcn_mfma_f32_16x16x32_bf16(pf, vf, acc[df], 0, 0, 0);
      }
    }
    __syncthreads();
  }
  // epilogue: normalize and store
  float l0 = 1.0f / __shfl(lrun, 4 * g + 0, 16);
  float l1 = 1.0f / __shfl(lrun, 4 * g + 1, 16);
  float l2 = 1.0f / __shfl(lrun, 4 * g + 2, 16);
  float l3 = 1.0f / __shfl(lrun, 4 * g + 3, 16);
  unsigned short* op = ctxb + (bS + qt * 128 + wid * 16 + 4 * g) * HID + h * HD + lr;
#pragma unroll
  for (int df = 0; df < 4; df++) {
    op[0 * HID + df * 16] = f2bf(acc[df][0] * l0);
    op[1 * HID + df * 16] = f2bf(acc[df][1] * l1);
    op[2 * HID + df * 16] = f2bf(acc[df][2] * l2);
    op[3 * HID + df * 16] = f2bf(acc[df][3] * l3);
  }
}

extern "C" void kernel_launch(void* const* d_in, const int* in_sizes, int n_in,
                              void* d_out, int out_size, void* d_ws, size_t ws_size,
                              hipStream_t stream) {
  const float* x = (const float*)d_in[0];
  const unsigned char* mask = (const unsigned char*)d_in[1];
  const float* Wq = (const float*)d_in[2];
  const float* bq = (const float*)d_in[3];
  const float* Wk = (const float*)d_in[4];
  const float* bk = (const float*)d_in[5];
  const float* Wv = (const float*)d_in[6];
  const float* bv = (const float*)d_in[7];
  const float* Wo = (const float*)d_in[8];
  const float* bo = (const float*)d_in[9];
  float* out = (float*)d_out;

  char* ws = (char*)d_ws;
  const size_t MiB = 1024 * 1024;
  unsigned short* xb  = (unsigned short*)(ws + 0 * MiB);   // 8 MiB
  unsigned short* nxb = (unsigned short*)(ws + 8 * MiB);   // 8 MiB
  unsigned short* Wb  = (unsigned short*)(ws + 16 * MiB);  // 8 MiB
  unsigned short* QKV = (unsigned short*)(ws + 24 * MiB);  // 24 MiB [4096][3072]
  unsigned short* D2  = (unsigned short*)(ws + 48 * MiB);  // 16 MiB [2][2048][2048] bf16
  unsigned short* ctx = (unsigned short*)(ws + 64 * MiB);  // 8 MiB

  convert_w_kernel<<<2048, 256, 0, stream>>>(Wq, Wk, Wv, Wo, Wb);
  rownorm_kernel<<<NB * SEQ, 256, 0, stream>>>(x, xb, nxb);
  // fused QKV projection
  gemm_nt<0><<<dim3(24, 32, 1), 256, 0, stream>>>(
      xb, 0, Wb, 0, QKV, 0, 3 * HID, NB * SEQ, 3 * HID, HID, bq, bk, bv, nullptr);
  // diversity bias (log2 domain, bf16): D' = -gamma*log2e*sim + mask*(-1e30)
  gemm_nt<1><<<dim3(16, 16, 2), 256, 0, stream>>>(
      nxb, (long)SEQ * HID, nxb, (long)SEQ * HID, D2, (long)SEQ * SEQ, SEQ,
      SEQ, SEQ, HID, nullptr, nullptr, nullptr, mask);
  // flash attention over all heads
  flash_kernel<<<dim3(SEQ / 128, NH, NB), 512, 0, stream>>>(QKV, D2, ctx);
  // output projection
  gemm_nt<2><<<dim3(8, 32, 1), 256, 0, stream>>>(
      ctx, 0, Wb + (size_t)3 * HID * HID, 0, out, 0, HID, NB * SEQ, HID, HID,
      bo, nullptr, nullptr, nullptr);
}

// Round 4
// 220.646 us; speedup vs baseline: 1.3308x; 1.0487x over previous
//
#include <hip/hip_runtime.h>

#define HID 1024
#define SEQ 2048
#define NB 2
#define NH 16
#define HD 64

// 0.125 * log2(e)  (1/sqrt(64) folded into log2 domain)
#define C1 0.1803368801111204f
// gamma * log2(e)
#define C2 0.7213475204444817f

typedef __attribute__((ext_vector_type(8))) short bf16x8;
typedef __attribute__((ext_vector_type(8))) unsigned short u16x8;
typedef __attribute__((ext_vector_type(4))) float f32x4;

__device__ __forceinline__ unsigned short f2bf(float f) {
  unsigned u = __builtin_bit_cast(unsigned, f);
  u += 0x7fffu + ((u >> 16) & 1u);
  return (unsigned short)(u >> 16);
}
__device__ __forceinline__ float bf2f(unsigned short u) {
  return __builtin_bit_cast(float, ((unsigned)u) << 16);
}

#define GLOAD16(gsrc, ldst)                                                     \
  __builtin_amdgcn_global_load_lds(                                             \
      (const __attribute__((address_space(1))) void*)(gsrc),                    \
      (__attribute__((address_space(3))) void*)(ldst), 16, 0, 0)

// ---- convert the 4 weight matrices f32 -> bf16 into one contiguous buffer ----
__global__ __launch_bounds__(256) void convert_w_kernel(
    const float* __restrict__ Wq, const float* __restrict__ Wk,
    const float* __restrict__ Wv, const float* __restrict__ Wo,
    unsigned short* __restrict__ Wb) {
  int i = blockIdx.x * 256 + threadIdx.x;
  const int per = (HID * HID) / 8;
  int m = i / per;
  const float* sp = (m == 0) ? Wq : (m == 1) ? Wk : (m == 2) ? Wv : Wo;
  int j = (i - m * per) * 8;
  const float4* p = reinterpret_cast<const float4*>(sp + j);
  float4 a = p[0], b = p[1];
  u16x8 o;
  o[0] = f2bf(a.x); o[1] = f2bf(a.y); o[2] = f2bf(a.z); o[3] = f2bf(a.w);
  o[4] = f2bf(b.x); o[5] = f2bf(b.y); o[6] = f2bf(b.z); o[7] = f2bf(b.w);
  *reinterpret_cast<u16x8*>(Wb + (size_t)i * 8) = o;
}

// ---- per-row L2 norm of x; emit x (bf16) and normalized x (bf16) ----
__global__ __launch_bounds__(256) void rownorm_kernel(
    const float* __restrict__ x, unsigned short* __restrict__ xb,
    unsigned short* __restrict__ nxb) {
  int row = blockIdx.x, tid = threadIdx.x;
  const float4 v = reinterpret_cast<const float4*>(x + (size_t)row * HID)[tid];
  float ss = v.x * v.x + v.y * v.y + v.z * v.z + v.w * v.w;
#pragma unroll
  for (int off = 32; off; off >>= 1) ss += __shfl_xor(ss, off, 64);
  __shared__ float wsum[4];
  if ((tid & 63) == 0) wsum[tid >> 6] = ss;
  __syncthreads();
  float tot = wsum[0] + wsum[1] + wsum[2] + wsum[3];
  float inv = 1.0f / fmaxf(sqrtf(tot), 1e-12f);
  ushort4 a, b;
  a.x = f2bf(v.x); a.y = f2bf(v.y); a.z = f2bf(v.z); a.w = f2bf(v.w);
  b.x = f2bf(v.x * inv); b.y = f2bf(v.y * inv);
  b.z = f2bf(v.z * inv); b.w = f2bf(v.w * inv);
  reinterpret_cast<ushort4*>(xb  + (size_t)row * HID)[tid] = a;
  reinterpret_cast<ushort4*>(nxb + (size_t)row * HID)[tid] = b;
}

// ---- generic NT bf16 GEMM: C = A[M,K] * B[N,K]^T, f32 accum ----
template <int MODE>
__global__ __launch_bounds__(256) void gemm_nt(
    const unsigned short* __restrict__ A, long strideA,
    const unsigned short* __restrict__ B, long strideB,
    void* __restrict__ Cv, long strideC, int ldc,
    int M, int N, int K,
    const float* __restrict__ b0, const float* __restrict__ b1,
    const float* __restrict__ b2, const unsigned char* __restrict__ mask) {
  __shared__ __align__(16) unsigned short As[128][40];
  __shared__ __align__(16) unsigned short Bs[128][40];
  int tid = threadIdx.x, lane = tid & 63, wid = tid >> 6;
  int g = lane >> 4, lr = lane & 15;
  int wr = wid >> 1, wc = wid & 1;
  int m0 = blockIdx.y * 128, n0 = blockIdx.x * 128;
  const unsigned short* Ab = A + (size_t)blockIdx.z * strideA;
  const unsigned short* Bb = B + (size_t)blockIdx.z * strideB;
  f32x4 acc[4][4] = {};
  for (int k0 = 0; k0 < K; k0 += 32) {
#pragma unroll
    for (int p = 0; p < 2; p++) {
      int u = tid + p * 256;
      int row = u >> 2, chk = u & 3;
      *reinterpret_cast<u16x8*>(&As[row][chk * 8]) =
          *reinterpret_cast<const u16x8*>(Ab + (size_t)(m0 + row) * K + k0 + chk * 8);
      *reinterpret_cast<u16x8*>(&Bs[row][chk * 8]) =
          *reinterpret_cast<const u16x8*>(Bb + (size_t)(n0 + row) * K + k0 + chk * 8);
    }
    __syncthreads();
    bf16x8 af[4], bfr[4];
#pragma unroll
    for (int i = 0; i < 4; i++) {
      af[i]  = *reinterpret_cast<const bf16x8*>(&As[wr * 64 + i * 16 + lr][g * 8]);
      bfr[i] = *reinterpret_cast<const bf16x8*>(&Bs[wc * 64 + i * 16 + lr][g * 8]);
    }
#pragma unroll
    for (int i = 0; i < 4; i++)
#pragma unroll
      for (int j = 0; j < 4; j++)
        acc[i][j] = __builtin_amdgcn_mfma_f32_16x16x32_bf16(af[i], bfr[j], acc[i][j], 0, 0, 0);
    __syncthreads();
  }
#pragma unroll
  for (int i = 0; i < 4; i++)
#pragma unroll
    for (int j = 0; j < 4; j++) {
      int col = n0 + wc * 64 + j * 16 + lr;
#pragma unroll
      for (int r = 0; r < 4; r++) {
        int row = m0 + wr * 64 + i * 16 + 4 * g + r;
        float v = acc[i][j][r];
        if (MODE == 0) {
          const float* bp = (col < 1024) ? b0 : (col < 2048 ? b1 : b2);
          v += bp[col & 1023];
          ((unsigned short*)Cv)[(size_t)blockIdx.z * strideC + (size_t)row * ldc + col] = f2bf(v);
        } else if (MODE == 1) {
          float t = -C2 * v + (mask[(size_t)row * N + col] ? -1e30f : 0.0f);
          ((unsigned short*)Cv)[(size_t)blockIdx.z * strideC + (size_t)row * ldc + col] = f2bf(t);
        } else {
          v += b0[col];
          ((float*)Cv)[(size_t)blockIdx.z * strideC + (size_t)row * ldc + col] = v;
        }
      }
    }
}

// ---- flash attention v3: 4 waves x 32 q-rows, KVBLK=64, swapped QK^T ----
// lane (g,lr) holds S^T[key=kc*16+4g+r][q=qh*16+lr]; softmax per-lane along keys.
__global__ __launch_bounds__(256, 3) void flash_kernel(
    const unsigned short* __restrict__ QKV,  // [4096][3072] bf16 (Q|K|V)
    const unsigned short* __restrict__ D2,   // [2][2048][2048] bf16 log2-bias
    unsigned short* __restrict__ ctxb) {     // [4096][1024] bf16
  int qt = blockIdx.x, h = blockIdx.y, b = blockIdx.z;
  int tid = threadIdx.x, wid = tid >> 6, lane = tid & 63;
  int g = lane >> 4, lr = lane & 15;
  __shared__ __align__(16) unsigned short Ks[2][64 * 64];
  __shared__ __align__(16) unsigned short Vt[2][64 * 64];
  __shared__ __align__(16) unsigned short Pl[4][32 * 72];
  const size_t ld = 3 * HID;
  const size_t bS = (size_t)b * SEQ;
  const int qbase = qt * 128 + wid * 32;

  // Q fragments (B operand): rows qbase + qh*16 + lr; lane group g holds d=8g+j
  const unsigned short* qp = QKV + (bS + qbase + lr) * ld + h * HD + g * 8;
  bf16x8 qf00 = *reinterpret_cast<const bf16x8*>(qp);
  bf16x8 qf01 = *reinterpret_cast<const bf16x8*>(qp + 32);
  bf16x8 qf10 = *reinterpret_cast<const bf16x8*>(qp + 16 * ld);
  bf16x8 qf11 = *reinterpret_cast<const bf16x8*>(qp + 16 * ld + 32);

  // K staging via global_load_lds with pre-swizzled source:
  // LDS slot (row, c') = K[row][c' ^ (row&7)], row&7 == lane>>3
  const unsigned short* gK0 = QKV + (bS + wid * 16 + (lane >> 3)) * ld + HID + h * HD
                              + (((lane & 7) ^ (lane >> 3)) << 3);
  const unsigned short* gK1 = gK0 + 8 * ld;

  // V staging: reg -> swizzled transposed scalar writes (conflict-free)
  const int vr0 = tid >> 3, ch = tid & 7;
  const unsigned short* gV0 = QKV + (bS + vr0) * ld + 2 * HID + h * HD + (ch << 3);
  const unsigned short* gV1 = gV0 + 32 * ld;
  const int kr3 = vr0 & 7;
  const int kb0v = vr0 >> 3, kb1v = kb0v + 4;
  const int vtbase = ch * 512 + kr3;
  const int pre0 = (kb0v ^ ch) & 7, pre1 = (kb1v ^ ch) & 7;

  // log2-domain bias rows (lane owns q = qbase + qh*16 + lr)
  const unsigned short* bD0 = D2 + (size_t)b * SEQ * SEQ
                              + (size_t)(qbase + lr) * SEQ + 4 * g;
  const unsigned short* bD1 = bD0 + (size_t)16 * SEQ;

  // prologue: stage tile 0 into buffer 0
  GLOAD16(gK0, &Ks[0][wid * 1024]);
  GLOAD16(gK1, &Ks[0][wid * 1024 + 512]);
  {
    u16x8 v0 = *reinterpret_cast<const u16x8*>(gV0);
    u16x8 v1 = *reinterpret_cast<const u16x8*>(gV1);
#pragma unroll
    for (int i = 0; i < 8; i++) {
      Vt[0][vtbase + i * 64 + ((pre0 ^ i) << 3)] = v0[i];
      Vt[0][vtbase + i * 64 + ((pre1 ^ i) << 3)] = v1[i];
    }
  }
  __syncthreads();

  f32x4 acc[2][4] = {};
  f32x4 rsacc[2] = {};
  float mrun[2] = {-1e30f, -1e30f};
  const int kb0 = lr * 64 + ((g ^ (lr & 7)) << 3);
  bf16x8 ones;
#pragma unroll
  for (int i = 0; i < 8; i++) ones[i] = 0x3F80;  // bf16 1.0

  for (int kt = 0; kt < 32; ++kt) {
    const int cb = kt & 1;
    const unsigned short* ks = &Ks[cb][0];
    const unsigned short* vt = &Vt[cb][0];
    u16x8 vv0 = {}, vv1 = {};
    if (kt < 31) {  // prefetch next tile (T14: issue early, write late)
      GLOAD16(gK0 + (size_t)(kt + 1) * 64 * ld, &Ks[cb ^ 1][wid * 1024]);
      GLOAD16(gK1 + (size_t)(kt + 1) * 64 * ld, &Ks[cb ^ 1][wid * 1024 + 512]);
      vv0 = *reinterpret_cast<const u16x8*>(gV0 + (size_t)(kt + 1) * 64 * ld);
      vv1 = *reinterpret_cast<const u16x8*>(gV1 + (size_t)(kt + 1) * 64 * ld);
    }
    // bias loads (contiguous along key)
    ushort4 bv[2][4];
#pragma unroll
    for (int kc = 0; kc < 4; kc++) {
      bv[0][kc] = *reinterpret_cast<const ushort4*>(bD0 + kt * 64 + kc * 16);
      bv[1][kc] = *reinterpret_cast<const ushort4*>(bD1 + kt * 64 + kc * 16);
    }
    // S^T = K Q^T  (A = K frag shared across both q-halves)
    f32x4 s[2][4];
#pragma unroll
    for (int kc = 0; kc < 4; kc++) {
      bf16x8 kf0 = *reinterpret_cast<const bf16x8*>(ks + kc * 1024 + kb0);
      bf16x8 kf1 = *reinterpret_cast<const bf16x8*>(ks + kc * 1024 + (kb0 ^ 32));
      f32x4 z0 = {};
      z0 = __builtin_amdgcn_mfma_f32_16x16x32_bf16(kf0, qf00, z0, 0, 0, 0);
      s[0][kc] = __builtin_amdgcn_mfma_f32_16x16x32_bf16(kf1, qf01, z0, 0, 0, 0);
      f32x4 z1 = {};
      z1 = __builtin_amdgcn_mfma_f32_16x16x32_bf16(kf0, qf10, z1, 0, 0, 0);
      s[1][kc] = __builtin_amdgcn_mfma_f32_16x16x32_bf16(kf1, qf11, z1, 0, 0, 0);
    }
    // scale + bias (log2 domain), per-lane max per q-half
    float mx[2];
#pragma unroll
    for (int qh = 0; qh < 2; qh++) {
      float m01, m23;
#pragma unroll
      for (int kc = 0; kc < 4; kc++) {
        s[qh][kc][0] = fmaf(s[qh][kc][0], C1, bf2f(bv[qh][kc].x));
        s[qh][kc][1] = fmaf(s[qh][kc][1], C1, bf2f(bv[qh][kc].y));
        s[qh][kc][2] = fmaf(s[qh][kc][2], C1, bf2f(bv[qh][kc].z));
        s[qh][kc][3] = fmaf(s[qh][kc][3], C1, bf2f(bv[qh][kc].w));
      }
      m01 = fmaxf(fmaxf(s[qh][0][0], s[qh][0][1]), fmaxf(s[qh][0][2], s[qh][0][3]));
      m23 = fmaxf(fmaxf(s[qh][1][0], s[qh][1][1]), fmaxf(s[qh][1][2], s[qh][1][3]));
      m01 = fmaxf(m01, fmaxf(fmaxf(s[qh][2][0], s[qh][2][1]), fmaxf(s[qh][2][2], s[qh][2][3])));
      m23 = fmaxf(m23, fmaxf(fmaxf(s[qh][3][0], s[qh][3][1]), fmaxf(s[qh][3][2], s[qh][3][3])));
      mx[qh] = fmaxf(m01, m23);
    }
    // defer-max (T13): only rescale when some row's max grew past THR=8
    if (!__all((mx[0] <= mrun[0] + 8.0f) & (mx[1] <= mrun[1] + 8.0f))) {
#pragma unroll
      for (int qh = 0; qh < 2; qh++) {
        float M = mx[qh];
        M = fmaxf(M, __shfl_xor(M, 16, 64));
        M = fmaxf(M, __shfl_xor(M, 32, 64));
        M = fmaxf(M, mrun[qh]);
        float sc = exp2f(mrun[qh] - M);
        mrun[qh] = M;
        float s0 = __shfl(sc, 4 * g + 0, 16), s1 = __shfl(sc, 4 * g + 1, 16);
        float s2 = __shfl(sc, 4 * g + 2, 16), s3 = __shfl(sc, 4 * g + 3, 16);
#pragma unroll
        for (int df = 0; df < 4; df++) {
          acc[qh][df][0] *= s0; acc[qh][df][1] *= s1;
          acc[qh][df][2] *= s2; acc[qh][df][3] *= s3;
        }
        rsacc[qh][0] *= s0; rsacc[qh][1] *= s1;
        rsacc[qh][2] *= s2; rsacc[qh][3] *= s3;
      }
    }
    // P = exp2(s - mrun); pack by truncation (consistent num/denom -> bias cancels)
#pragma unroll
    for (int qh = 0; qh < 2; qh++) {
#pragma unroll
      for (int kc = 0; kc < 4; kc++) {
        float p0 = exp2f(s[qh][kc][0] - mrun[qh]);
        float p1 = exp2f(s[qh][kc][1] - mrun[qh]);
        float p2 = exp2f(s[qh][kc][2] - mrun[qh]);
        float p3 = exp2f(s[qh][kc][3] - mrun[qh]);
        uint2 w;
        w.x = __builtin_amdgcn_perm(__builtin_bit_cast(unsigned, p1),
                                    __builtin_bit_cast(unsigned, p0), 0x07060302u);
        w.y = __builtin_amdgcn_perm(__builtin_bit_cast(unsigned, p3),
                                    __builtin_bit_cast(unsigned, p2), 0x07060302u);
        *reinterpret_cast<uint2*>(&Pl[wid][(qh * 16 + lr) * 72 + kc * 16 + 4 * g]) = w;
      }
    }
    // write next V tile (vv loads drained here, overlapped with softmax above)
    if (kt < 31) {
#pragma unroll
      for (int i = 0; i < 8; i++) {
        Vt[cb ^ 1][vtbase + i * 64 + ((pre0 ^ i) << 3)] = vv0[i];
        Vt[cb ^ 1][vtbase + i * 64 + ((pre1 ^ i) << 3)] = vv1[i];
      }
    }
    // ctx += P V ; l += P . ones   (vf shared across q-halves)
#pragma unroll
    for (int c2 = 0; c2 < 2; c2++) {
      bf16x8 vf[4];
#pragma unroll
      for (int df = 0; df < 4; df++) {
        int blk = ((4 * c2 + g) ^ (lr & 7) ^ ((df * 2 + (lr >> 3)) & 7)) & 7;
        vf[df] = *reinterpret_cast<const bf16x8*>(vt + (df * 16 + lr) * 64 + (blk << 3));
      }
#pragma unroll
      for (int qh = 0; qh < 2; qh++) {
        bf16x8 pf = *reinterpret_cast<const bf16x8*>(
            &Pl[wid][(qh * 16 + lr) * 72 + c2 * 32 + g * 8]);
        rsacc[qh] = __builtin_amdgcn_mfma_f32_16x16x32_bf16(pf, ones, rsacc[qh], 0, 0, 0);
#pragma unroll
        for (int df = 0; df < 4; df++)
          acc[qh][df] = __builtin_amdgcn_mfma_f32_16x16x32_bf16(pf, vf[df], acc[qh][df], 0, 0, 0);
      }
    }
    __syncthreads();
  }
  // epilogue: normalize and store (stats already in acc row layout)
#pragma unroll
  for (int qh = 0; qh < 2; qh++) {
    float l0 = 1.0f / rsacc[qh][0], l1 = 1.0f / rsacc[qh][1];
    float l2 = 1.0f / rsacc[qh][2], l3 = 1.0f / rsacc[qh][3];
    unsigned short* op = ctxb + (bS + qbase + qh * 16 + 4 * g) * HID + h * HD + lr;
#pragma unroll
    for (int df = 0; df < 4; df++) {
      op[0 * HID + df * 16] = f2bf(acc[qh][df][0] * l0);
      op[1 * HID + df * 16] = f2bf(acc[qh][df][1] * l1);
      op[2 * HID + df * 16] = f2bf(acc[qh][df][2] * l2);
      op[3 * HID + df * 16] = f2bf(acc[qh][df][3] * l3);
    }
  }
}

extern "C" void kernel_launch(void* const* d_in, const int* in_sizes, int n_in,
                              void* d_out, int out_size, void* d_ws, size_t ws_size,
                              hipStream_t stream) {
  const float* x = (const float*)d_in[0];
  const unsigned char* mask = (const unsigned char*)d_in[1];
  const float* Wq = (const float*)d_in[2];
  const float* bq = (const float*)d_in[3];
  const float* Wk = (const float*)d_in[4];
  const float* bk = (const float*)d_in[5];
  const float* Wv = (const float*)d_in[6];
  const float* bv = (const float*)d_in[7];
  const float* Wo = (const float*)d_in[8];
  const float* bo = (const float*)d_in[9];
  float* out = (float*)d_out;

  char* ws = (char*)d_ws;
  const size_t MiB = 1024 * 1024;
  unsigned short* xb  = (unsigned short*)(ws + 0 * MiB);   // 8 MiB
  unsigned short* nxb = (unsigned short*)(ws + 8 * MiB);   // 8 MiB
  unsigned short* Wb  = (unsigned short*)(ws + 16 * MiB);  // 8 MiB
  unsigned short* QKV = (unsigned short*)(ws + 24 * MiB);  // 24 MiB [4096][3072]
  unsigned short* D2  = (unsigned short*)(ws + 48 * MiB);  // 16 MiB bf16 log2-bias
  unsigned short* ctx = (unsigned short*)(ws + 64 * MiB);  // 8 MiB

  convert_w_kernel<<<2048, 256, 0, stream>>>(Wq, Wk, Wv, Wo, Wb);
  rownorm_kernel<<<NB * SEQ, 256, 0, stream>>>(x, xb, nxb);
  // fused QKV projection
  gemm_nt<0><<<dim3(24, 32, 1), 256, 0, stream>>>(
      xb, 0, Wb, 0, QKV, 0, 3 * HID, NB * SEQ, 3 * HID, HID, bq, bk, bv, nullptr);
  // diversity bias (log2 domain, bf16): D' = -gamma*log2e*sim + mask*(-1e30)
  gemm_nt<1><<<dim3(16, 16, 2), 256, 0, stream>>>(
      nxb, (long)SEQ * HID, nxb, (long)SEQ * HID, D2, (long)SEQ * SEQ, SEQ,
      SEQ, SEQ, HID, nullptr, nullptr, nullptr, mask);
  // flash attention over all heads
  flash_kernel<<<dim3(SEQ / 128, NH, NB), 256, 0, stream>>>(QKV, D2, ctx);
  // output projection
  gemm_nt<2><<<dim3(8, 32, 1), 256, 0, stream>>>(
      ctx, 0, Wb + (size_t)3 * HID * HID, 0, out, 0, HID, NB * SEQ, HID, HID,
      bo, nullptr, nullptr, nullptr);
}

// Round 5
// 211.851 us; speedup vs baseline: 1.3860x; 1.0415x over previous
//
#include <hip/hip_runtime.h>

#define HID 1024
#define SEQ 2048
#define NB 2
#define NH 16
#define HD 64

// 0.125 * log2(e)  (1/sqrt(64) folded into log2 domain)
#define C1 0.1803368801111204f
// gamma * log2(e)
#define C2 0.7213475204444817f

typedef __attribute__((ext_vector_type(8))) short bf16x8;
typedef __attribute__((ext_vector_type(8))) unsigned short u16x8;
typedef __attribute__((ext_vector_type(4))) float f32x4;

__device__ __forceinline__ unsigned short f2bf(float f) {
  unsigned u = __builtin_bit_cast(unsigned, f);
  u += 0x7fffu + ((u >> 16) & 1u);
  return (unsigned short)(u >> 16);
}
__device__ __forceinline__ float bf2f(unsigned short u) {
  return __builtin_bit_cast(float, ((unsigned)u) << 16);
}

#define GLOAD16(gsrc, ldst)                                                     \
  __builtin_amdgcn_global_load_lds(                                             \
      (const __attribute__((address_space(1))) void*)(gsrc),                    \
      (__attribute__((address_space(3))) void*)(ldst), 16, 0, 0)

// ---- convert the 4 weight matrices f32 -> bf16 into one contiguous buffer ----
__global__ __launch_bounds__(256) void convert_w_kernel(
    const float* __restrict__ Wq, const float* __restrict__ Wk,
    const float* __restrict__ Wv, const float* __restrict__ Wo,
    unsigned short* __restrict__ Wb) {
  int i = blockIdx.x * 256 + threadIdx.x;
  const int per = (HID * HID) / 8;
  int m = i / per;
  const float* sp = (m == 0) ? Wq : (m == 1) ? Wk : (m == 2) ? Wv : Wo;
  int j = (i - m * per) * 8;
  const float4* p = reinterpret_cast<const float4*>(sp + j);
  float4 a = p[0], b = p[1];
  u16x8 o;
  o[0] = f2bf(a.x); o[1] = f2bf(a.y); o[2] = f2bf(a.z); o[3] = f2bf(a.w);
  o[4] = f2bf(b.x); o[5] = f2bf(b.y); o[6] = f2bf(b.z); o[7] = f2bf(b.w);
  *reinterpret_cast<u16x8*>(Wb + (size_t)i * 8) = o;
}

// ---- per-row L2 norm of x; emit x (bf16) and normalized x (bf16) ----
__global__ __launch_bounds__(256) void rownorm_kernel(
    const float* __restrict__ x, unsigned short* __restrict__ xb,
    unsigned short* __restrict__ nxb) {
  int row = blockIdx.x, tid = threadIdx.x;
  const float4 v = reinterpret_cast<const float4*>(x + (size_t)row * HID)[tid];
  float ss = v.x * v.x + v.y * v.y + v.z * v.z + v.w * v.w;
#pragma unroll
  for (int off = 32; off; off >>= 1) ss += __shfl_xor(ss, off, 64);
  __shared__ float wsum[4];
  if ((tid & 63) == 0) wsum[tid >> 6] = ss;
  __syncthreads();
  float tot = wsum[0] + wsum[1] + wsum[2] + wsum[3];
  float inv = 1.0f / fmaxf(sqrtf(tot), 1e-12f);
  ushort4 a, b;
  a.x = f2bf(v.x); a.y = f2bf(v.y); a.z = f2bf(v.z); a.w = f2bf(v.w);
  b.x = f2bf(v.x * inv); b.y = f2bf(v.y * inv);
  b.z = f2bf(v.z * inv); b.w = f2bf(v.w * inv);
  reinterpret_cast<ushort4*>(xb  + (size_t)row * HID)[tid] = a;
  reinterpret_cast<ushort4*>(nxb + (size_t)row * HID)[tid] = b;
}

// ---- generic NT bf16 GEMM: C = A[M,K] * B[N,K]^T, f32 accum ----
// Staging via global_load_lds width=16 into unpadded [128][32] tiles
// (frag reads are bank-structural-floor: bank = 16*(lr&1)+4g+j).
template <int MODE>
__global__ __launch_bounds__(256) void gemm_nt(
    const unsigned short* __restrict__ A, long strideA,
    const unsigned short* __restrict__ B, long strideB,
    void* __restrict__ Cv, long strideC, int ldc,
    int M, int N, int K,
    const float* __restrict__ b0, const float* __restrict__ b1,
    const float* __restrict__ b2, const unsigned char* __restrict__ mask) {
  __shared__ __align__(16) unsigned short As[128 * 32];
  __shared__ __align__(16) unsigned short Bs[128 * 32];
  int tid = threadIdx.x, lane = tid & 63, wid = tid >> 6;
  int g = lane >> 4, lr = lane & 15;
  int wr = wid >> 1, wc = wid & 1;
  int m0 = blockIdx.y * 128, n0 = blockIdx.x * 128;
  const unsigned short* Ab = A + (size_t)blockIdx.z * strideA
      + (size_t)(m0 + wid * 32 + (lane >> 2)) * K + (lane & 3) * 8;
  const unsigned short* Bb = B + (size_t)blockIdx.z * strideB
      + (size_t)(n0 + wid * 32 + (lane >> 2)) * K + (lane & 3) * 8;
  unsigned short* la = As + wid * 1024;
  unsigned short* lb = Bs + wid * 1024;
  f32x4 acc[4][4] = {};
  for (int k0 = 0; k0 < K; k0 += 32) {
    GLOAD16(Ab + k0, la);
    GLOAD16(Ab + 16 * K + k0, la + 512);
    GLOAD16(Bb + k0, lb);
    GLOAD16(Bb + 16 * K + k0, lb + 512);
    __syncthreads();
    bf16x8 af[4], bfr[4];
#pragma unroll
    for (int i = 0; i < 4; i++) {
      af[i]  = *reinterpret_cast<const bf16x8*>(&As[(wr * 64 + i * 16 + lr) * 32 + g * 8]);
      bfr[i] = *reinterpret_cast<const bf16x8*>(&Bs[(wc * 64 + i * 16 + lr) * 32 + g * 8]);
    }
#pragma unroll
    for (int i = 0; i < 4; i++)
#pragma unroll
      for (int j = 0; j < 4; j++)
        acc[i][j] = __builtin_amdgcn_mfma_f32_16x16x32_bf16(af[i], bfr[j], acc[i][j], 0, 0, 0);
    __syncthreads();
  }
#pragma unroll
  for (int i = 0; i < 4; i++)
#pragma unroll
    for (int j = 0; j < 4; j++) {
      int col = n0 + wc * 64 + j * 16 + lr;
#pragma unroll
      for (int r = 0; r < 4; r++) {
        int row = m0 + wr * 64 + i * 16 + 4 * g + r;
        float v = acc[i][j][r];
        if (MODE == 0) {
          const float* bp = (col < 1024) ? b0 : (col < 2048 ? b1 : b2);
          v += bp[col & 1023];
          ((unsigned short*)Cv)[(size_t)blockIdx.z * strideC + (size_t)row * ldc + col] = f2bf(v);
        } else if (MODE == 1) {
          float t = -C2 * v + (mask[(size_t)row * N + col] ? -1e30f : 0.0f);
          ((unsigned short*)Cv)[(size_t)blockIdx.z * strideC + (size_t)row * ldc + col] = f2bf(t);
        } else {
          v += b0[col];
          ((float*)Cv)[(size_t)blockIdx.z * strideC + (size_t)row * ldc + col] = v;
        }
      }
    }
}

// ---- flash attention v4: 4 waves x 16 q-rows (QBLK=64), KVBLK=64 ----
// grid (h, qt, b) so XCD = h%8 -> per-XCD K/V working set 2MB (L2-resident).
// lane (g,lr) holds S^T[key=kc*16+4g+r][q=lr]; softmax per-lane along keys.
__global__ __launch_bounds__(256, 4) void flash_kernel(
    const unsigned short* __restrict__ QKV,  // [4096][3072] bf16 (Q|K|V)
    const unsigned short* __restrict__ D2,   // [2][2048][2048] bf16 log2-bias
    unsigned short* __restrict__ ctxb) {     // [4096][1024] bf16
  int h = blockIdx.x, qt = blockIdx.y, b = blockIdx.z;
  int tid = threadIdx.x, wid = tid >> 6, lane = tid & 63;
  int g = lane >> 4, lr = lane & 15;
  __shared__ __align__(16) unsigned short Ks[2][64 * 64];  // 16 KiB
  __shared__ __align__(16) unsigned short Vt[2][64 * 64];  // 16 KiB
  __shared__ __align__(16) unsigned short Pl[4][16 * 64];  // 8 KiB (XOR-swizzled)
  const size_t ld = 3 * HID;
  const size_t bS = (size_t)b * SEQ;
  const int qbase = qt * 64 + wid * 16;

  // Q fragment (B operand): rows qbase+lr; lane group g holds d=8g+j (+32)
  const unsigned short* qp = QKV + (bS + qbase + lr) * ld + h * HD + g * 8;
  bf16x8 qf0 = *reinterpret_cast<const bf16x8*>(qp);
  bf16x8 qf1 = *reinterpret_cast<const bf16x8*>(qp + 32);

  // K staging via global_load_lds, pre-swizzled source:
  // LDS slot (row, c') = K[row][c' ^ (row&7)], row&7 == lane>>3
  const unsigned short* gK0 = QKV + (bS + wid * 16 + (lane >> 3)) * ld + HID + h * HD
                              + (((lane & 7) ^ (lane >> 3)) << 3);
  const unsigned short* gK1 = gK0 + 8 * ld;

  // V staging: reg -> swizzled transposed scalar writes (conflict-free)
  const int vr0 = tid >> 3, ch = tid & 7;
  const unsigned short* gV0 = QKV + (bS + vr0) * ld + 2 * HID + h * HD + (ch << 3);
  const unsigned short* gV1 = gV0 + 32 * ld;
  const int kr3 = vr0 & 7;
  const int kb0v = vr0 >> 3, kb1v = kb0v + 4;
  const int vtbase = ch * 512 + kr3;
  const int pre0 = (kb0v ^ ch) & 7, pre1 = (kb1v ^ ch) & 7;

  // log2-domain bias row (lane owns q = qbase + lr)
  const unsigned short* bD = D2 + (size_t)b * SEQ * SEQ
                             + (size_t)(qbase + lr) * SEQ + 4 * g;

  // prologue: stage tile 0 into buffer 0
  GLOAD16(gK0, &Ks[0][wid * 1024]);
  GLOAD16(gK1, &Ks[0][wid * 1024 + 512]);
  {
    u16x8 v0 = *reinterpret_cast<const u16x8*>(gV0);
    u16x8 v1 = *reinterpret_cast<const u16x8*>(gV1);
#pragma unroll
    for (int i = 0; i < 8; i++) {
      Vt[0][vtbase + i * 64 + ((pre0 ^ i) << 3)] = v0[i];
      Vt[0][vtbase + i * 64 + ((pre1 ^ i) << 3)] = v1[i];
    }
  }
  __syncthreads();

  f32x4 acc[4] = {};
  f32x4 rsacc = {};
  float mrun = -1e30f;
  const int kb0 = lr * 64 + ((g ^ (lr & 7)) << 3);
  const int plw = lr * 64;              // P row base
  const int plm = (lr & 7) << 3;        // P XOR mask (shorts)
  bf16x8 ones;
#pragma unroll
  for (int i = 0; i < 8; i++) ones[i] = 0x3F80;  // bf16 1.0

  for (int kt = 0; kt < 32; ++kt) {
    const int cb = kt & 1;
    const unsigned short* ks = &Ks[cb][0];
    const unsigned short* vt = &Vt[cb][0];
    u16x8 vv0 = {}, vv1 = {};
    if (kt < 31) {  // prefetch next tile (issue early, write late)
      GLOAD16(gK0 + (size_t)(kt + 1) * 64 * ld, &Ks[cb ^ 1][wid * 1024]);
      GLOAD16(gK1 + (size_t)(kt + 1) * 64 * ld, &Ks[cb ^ 1][wid * 1024 + 512]);
      vv0 = *reinterpret_cast<const u16x8*>(gV0 + (size_t)(kt + 1) * 64 * ld);
      vv1 = *reinterpret_cast<const u16x8*>(gV1 + (size_t)(kt + 1) * 64 * ld);
    }
    // bias loads (contiguous along key)
    ushort4 bv[4];
#pragma unroll
    for (int kc = 0; kc < 4; kc++)
      bv[kc] = *reinterpret_cast<const ushort4*>(bD + kt * 64 + kc * 16);

    // S^T = K Q^T  (A = K frag, B = Q frag)
    f32x4 s[4];
#pragma unroll
    for (int kc = 0; kc < 4; kc++) {
      bf16x8 kf0 = *reinterpret_cast<const bf16x8*>(ks + kc * 1024 + kb0);
      bf16x8 kf1 = *reinterpret_cast<const bf16x8*>(ks + kc * 1024 + (kb0 ^ 32));
      f32x4 z = {};
      z = __builtin_amdgcn_mfma_f32_16x16x32_bf16(kf0, qf0, z, 0, 0, 0);
      s[kc] = __builtin_amdgcn_mfma_f32_16x16x32_bf16(kf1, qf1, z, 0, 0, 0);
    }
    // scale + bias (log2 domain), per-lane max
    float mx;
    {
      float m01, m23;
#pragma unroll
      for (int kc = 0; kc < 4; kc++) {
        s[kc][0] = fmaf(s[kc][0], C1, bf2f(bv[kc].x));
        s[kc][1] = fmaf(s[kc][1], C1, bf2f(bv[kc].y));
        s[kc][2] = fmaf(s[kc][2], C1, bf2f(bv[kc].z));
        s[kc][3] = fmaf(s[kc][3], C1, bf2f(bv[kc].w));
      }
      m01 = fmaxf(fmaxf(s[0][0], s[0][1]), fmaxf(s[0][2], s[0][3]));
      m23 = fmaxf(fmaxf(s[1][0], s[1][1]), fmaxf(s[1][2], s[1][3]));
      m01 = fmaxf(m01, fmaxf(fmaxf(s[2][0], s[2][1]), fmaxf(s[2][2], s[2][3])));
      m23 = fmaxf(m23, fmaxf(fmaxf(s[3][0], s[3][1]), fmaxf(s[3][2], s[3][3])));
      mx = fmaxf(m01, m23);
    }
    // defer-max (T13): only rescale when some row's max grew past THR=8
    if (!__all(mx <= mrun + 8.0f)) {
      float M = mx;
      M = fmaxf(M, __shfl_xor(M, 16, 64));
      M = fmaxf(M, __shfl_xor(M, 32, 64));
      M = fmaxf(M, mrun);
      float sc = exp2f(mrun - M);
      mrun = M;
      float s0 = __shfl(sc, 4 * g + 0, 16), s1 = __shfl(sc, 4 * g + 1, 16);
      float s2 = __shfl(sc, 4 * g + 2, 16), s3 = __shfl(sc, 4 * g + 3, 16);
#pragma unroll
      for (int df = 0; df < 4; df++) {
        acc[df][0] *= s0; acc[df][1] *= s1;
        acc[df][2] *= s2; acc[df][3] *= s3;
      }
      rsacc[0] *= s0; rsacc[1] *= s1; rsacc[2] *= s2; rsacc[3] *= s3;
    }
    // P = exp2(s - mrun); pack by truncation (consistent num/denom)
#pragma unroll
    for (int kc = 0; kc < 4; kc++) {
      float p0 = exp2f(s[kc][0] - mrun);
      float p1 = exp2f(s[kc][1] - mrun);
      float p2 = exp2f(s[kc][2] - mrun);
      float p3 = exp2f(s[kc][3] - mrun);
      uint2 w;
      w.x = __builtin_amdgcn_perm(__builtin_bit_cast(unsigned, p1),
                                  __builtin_bit_cast(unsigned, p0), 0x07060302u);
      w.y = __builtin_amdgcn_perm(__builtin_bit_cast(unsigned, p3),
                                  __builtin_bit_cast(unsigned, p2), 0x07060302u);
      *reinterpret_cast<uint2*>(&Pl[wid][plw + ((kc * 16 + 4 * g) ^ plm)]) = w;
    }
    // write next V tile (vv loads drained here, overlapped with softmax)
    if (kt < 31) {
#pragma unroll
      for (int i = 0; i < 8; i++) {
        Vt[cb ^ 1][vtbase + i * 64 + ((pre0 ^ i) << 3)] = vv0[i];
        Vt[cb ^ 1][vtbase + i * 64 + ((pre1 ^ i) << 3)] = vv1[i];
      }
    }
    // ctx += P V ; l += P . ones
#pragma unroll
    for (int c2 = 0; c2 < 2; c2++) {
      bf16x8 pf = *reinterpret_cast<const bf16x8*>(
          &Pl[wid][plw + ((c2 * 32 + g * 8) ^ plm)]);
      rsacc = __builtin_amdgcn_mfma_f32_16x16x32_bf16(pf, ones, rsacc, 0, 0, 0);
#pragma unroll
      for (int df = 0; df < 4; df++) {
        int blk = ((4 * c2 + g) ^ (lr & 7) ^ ((df * 2 + (lr >> 3)) & 7)) & 7;
        bf16x8 vf = *reinterpret_cast<const bf16x8*>(vt + (df * 16 + lr) * 64 + (blk << 3));
        acc[df] = __builtin_amdgcn_mfma_f32_16x16x32_bf16(pf, vf, acc[df], 0, 0, 0);
      }
    }
    __syncthreads();
  }
  // epilogue: normalize and store (stats already in acc row layout)
  float l0 = 1.0f / rsacc[0], l1 = 1.0f / rsacc[1];
  float l2 = 1.0f / rsacc[2], l3 = 1.0f / rsacc[3];
  unsigned short* op = ctxb + (bS + qbase + 4 * g) * HID + h * HD + lr;
#pragma unroll
  for (int df = 0; df < 4; df++) {
    op[0 * HID + df * 16] = f2bf(acc[df][0] * l0);
    op[1 * HID + df * 16] = f2bf(acc[df][1] * l1);
    op[2 * HID + df * 16] = f2bf(acc[df][2] * l2);
    op[3 * HID + df * 16] = f2bf(acc[df][3] * l3);
  }
}

extern "C" void kernel_launch(void* const* d_in, const int* in_sizes, int n_in,
                              void* d_out, int out_size, void* d_ws, size_t ws_size,
                              hipStream_t stream) {
  const float* x = (const float*)d_in[0];
  const unsigned char* mask = (const unsigned char*)d_in[1];
  const float* Wq = (const float*)d_in[2];
  const float* bq = (const float*)d_in[3];
  const float* Wk = (const float*)d_in[4];
  const float* bk = (const float*)d_in[5];
  const float* Wv = (const float*)d_in[6];
  const float* bv = (const float*)d_in[7];
  const float* Wo = (const float*)d_in[8];
  const float* bo = (const float*)d_in[9];
  float* out = (float*)d_out;

  char* ws = (char*)d_ws;
  const size_t MiB = 1024 * 1024;
  unsigned short* xb  = (unsigned short*)(ws + 0 * MiB);   // 8 MiB
  unsigned short* nxb = (unsigned short*)(ws + 8 * MiB);   // 8 MiB
  unsigned short* Wb  = (unsigned short*)(ws + 16 * MiB);  // 8 MiB
  unsigned short* QKV = (unsigned short*)(ws + 24 * MiB);  // 24 MiB [4096][3072]
  unsigned short* D2  = (unsigned short*)(ws + 48 * MiB);  // 16 MiB bf16 log2-bias
  unsigned short* ctx = (unsigned short*)(ws + 64 * MiB);  // 8 MiB

  convert_w_kernel<<<2048, 256, 0, stream>>>(Wq, Wk, Wv, Wo, Wb);
  rownorm_kernel<<<NB * SEQ, 256, 0, stream>>>(x, xb, nxb);
  // fused QKV projection
  gemm_nt<0><<<dim3(24, 32, 1), 256, 0, stream>>>(
      xb, 0, Wb, 0, QKV, 0, 3 * HID, NB * SEQ, 3 * HID, HID, bq, bk, bv, nullptr);
  // diversity bias (log2 domain, bf16): D' = -gamma*log2e*sim + mask*(-1e30)
  gemm_nt<1><<<dim3(16, 16, 2), 256, 0, stream>>>(
      nxb, (long)SEQ * HID, nxb, (long)SEQ * HID, D2, (long)SEQ * SEQ, SEQ,
      SEQ, SEQ, HID, nullptr, nullptr, nullptr, mask);
  // flash attention over all heads
  flash_kernel<<<dim3(NH, SEQ / 64, NB), 256, 0, stream>>>(QKV, D2, ctx);
  // output projection
  gemm_nt<2><<<dim3(8, 32, 1), 256, 0, stream>>>(
      ctx, 0, Wb + (size_t)3 * HID * HID, 0, out, 0, HID, NB * SEQ, HID, HID,
      bo, nullptr, nullptr, nullptr);
}